// Round 18
// baseline (78.651 us; speedup 1.0000x reference)
//
#include <hip/hip_runtime.h>
#include <hip/hip_bf16.h>

#define Tn 4096
#define Cn 768
#define Hn 12
#define DHn 64
#define BAND 128
#define QBLK 64
#define TJ 192        // BAND + QBLK staged keys per block
#define NTW 9         // 16-key tiles per wave (band window)
#define NE 5          // PV e-steps (32 keys each)

typedef __attribute__((ext_vector_type(8))) short short8;
typedef __attribute__((ext_vector_type(4))) short short4v;
typedef __attribute__((ext_vector_type(4))) float f32x4;

__device__ __forceinline__ float b2f(unsigned short u) {
  union { unsigned int i; float f; } z; z.i = ((unsigned int)u) << 16; return z.f;
}
__device__ __forceinline__ unsigned short f2b(float f) {
  union { float f; unsigned int i; } z; z.f = f;
  unsigned int r = z.i + 0x7FFFu + ((z.i >> 16) & 1u);
  return (unsigned short)(r >> 16);
}

// ---------------- prep: f32->bf16 convert + both weight transposes ----------------
__global__ __launch_bounds__(256) void k_prep(const float* __restrict__ x,
                                              unsigned short* __restrict__ x_bf,
                                              const float* __restrict__ Wqkv,
                                              unsigned short* __restrict__ WqkvT,
                                              const float* __restrict__ Wproj,
                                              unsigned short* __restrict__ WprojT) {
  __shared__ float tile[32][33];
  int b = blockIdx.x, tid = threadIdx.x;
  if (b < 512) {
    int n4 = Tn * Cn / 4;
    for (int i = b * 256 + tid; i < n4; i += 512 * 256) {
      float4 v = ((const float4*)x)[i];
      short4v o;
      o.x = (short)f2b(v.x); o.y = (short)f2b(v.y);
      o.z = (short)f2b(v.z); o.w = (short)f2b(v.w);
      ((short4v*)x_bf)[i] = o;
    }
    return;
  }
  const float* W; unsigned short* WT; int N, r;
  if (b < 2240) { r = b - 512; W = Wqkv; WT = WqkvT; N = 3 * Cn; }
  else          { r = b - 2240; W = Wproj; WT = WprojT; N = Cn; }
  int nb = N / 32;
  int n0 = (r % nb) * 32, k0 = (r / nb) * 32;
  int tx = tid & 31, ty = tid >> 5;   // 32 x 8
  for (int rr = ty; rr < 32; rr += 8) tile[rr][tx] = W[(size_t)(k0 + rr) * N + n0 + tx];
  __syncthreads();
  for (int rr = ty; rr < 32; rr += 8) WT[(size_t)(n0 + rr) * Cn + k0 + tx] = f2b(tile[tx][rr]);
}

// ======== GEMM staging: BK=64 variant (8 slots/row) and BK=128 variant (16 slots/row) ========
template<int ROWS, int NTHR>
__device__ __forceinline__ void stage_mat(const unsigned short* __restrict__ Gb,
                                          int K, unsigned short* buf, int k0, int tid) {
  constexpr int CHUNKS = ROWS * 8;
#pragma unroll
  for (int it = 0; it < CHUNKS / NTHR; ++it) {
    int c = it * NTHR + tid;
    int row = c >> 3;
    int kc = (c & 7) ^ (row & 7);
    const unsigned short* ga = Gb + (size_t)row * K + k0 + kc * 8;
    __builtin_amdgcn_global_load_lds((const __attribute__((address_space(1))) void*)ga,
                                     (__attribute__((address_space(3))) void*)(buf + c * 8),
                                     16, 0, 0);
  }
}

__device__ __forceinline__ short8 frag_read64(const unsigned short* buf, int row, int q) {
  int s = q ^ (row & 7);
  return *(const short8*)(buf + row * 64 + s * 8);
}

template<int ROWS, int NTHR>
__device__ __forceinline__ void stage_mat128(const unsigned short* __restrict__ Gb,
                                             int K, unsigned short* buf, int k0, int tid) {
  constexpr int CHUNKS = ROWS * 16;
#pragma unroll
  for (int it = 0; it < CHUNKS / NTHR; ++it) {
    int c = it * NTHR + tid;
    int row = c >> 4;
    int kc = (c & 15) ^ (row & 15);
    const unsigned short* ga = Gb + (size_t)row * K + k0 + kc * 8;
    __builtin_amdgcn_global_load_lds((const __attribute__((address_space(1))) void*)ga,
                                     (__attribute__((address_space(3))) void*)(buf + c * 8),
                                     16, 0, 0);
  }
}

__device__ __forceinline__ short8 frag_read128(const unsigned short* buf, int row, int q) {
  int s = q ^ (row & 15);
  return *(const short8*)(buf + row * 128 + s * 8);
}

// -------- QKV GEMM: 64x128 tile, BK=128 single-buffered simple loop, 48KB LDS, 3/CU --------
__global__ __launch_bounds__(256, 3) void k_gqkv(const unsigned short* __restrict__ A,
                                                 const unsigned short* __restrict__ BT,
                                                 const float* __restrict__ cosT,
                                                 const float* __restrict__ sinT,
                                                 unsigned short* __restrict__ qout,
                                                 unsigned short* __restrict__ kout,
                                                 unsigned short* __restrict__ vout) {
  __shared__ __align__(16) unsigned short Ls[24576];   // A 64x128 (8192 els) | B 128x128 (16384 els)
  int tid = threadIdx.x, lane = tid & 63, wave = tid >> 6;
  int lq = lane & 15, g = (lane >> 4) & 3;
  int wr = wave >> 1, wc = wave & 1;
  int nx = gridDim.x;
  int nwg = nx * gridDim.y;
  int lid = blockIdx.y * nx + blockIdx.x;
  int swz = (lid & 7) * (nwg >> 3) + (lid >> 3);
  int bx = swz % nx, by = swz / nx;
  int m0 = by * 64, n0 = bx * 128;
  const unsigned short* Ab = A + (size_t)m0 * Cn;
  const unsigned short* Bb = BT + (size_t)n0 * Cn;
  f32x4 acc[2][4] = {};
  const int NK = Cn >> 7;                     // 6
  for (int kt = 0; kt < NK; ++kt) {
    stage_mat128<64, 256>(Ab, Cn, Ls, kt << 7, tid);
    stage_mat128<128, 256>(Bb, Cn, Ls + 8192, kt << 7, tid);
    __syncthreads();                          // drains vmcnt -> loads visible
    const unsigned short* Ac = Ls;
    const unsigned short* Bc = Ls + 8192;
#pragma unroll
    for (int kk = 0; kk < 4; ++kk) {
      short8 a[2], b[4];
#pragma unroll
      for (int m = 0; m < 2; ++m) a[m] = frag_read128(Ac, wr * 32 + m * 16 + lq, kk * 4 + g);
#pragma unroll
      for (int n = 0; n < 4; ++n) b[n] = frag_read128(Bc, wc * 64 + n * 16 + lq, kk * 4 + g);
#pragma unroll
      for (int m = 0; m < 2; ++m)
#pragma unroll
        for (int n = 0; n < 4; ++n)
          acc[m][n] = __builtin_amdgcn_mfma_f32_16x16x32_bf16(a[m], b[n], acc[m][n], 0, 0, 0);
    }
    __syncthreads();                          // all reads done before next-stage overwrite
  }
  // epilogue: RoPE in-register, scatter to LDS, coalesced stores
  int col0 = n0 + wc * 64;
  int part = col0 / Cn;
  unsigned short* Lo = (unsigned short*)Ls;   // 64x128 out tile (16KB < 48KB)
#pragma unroll
  for (int m = 0; m < 2; ++m)
#pragma unroll
    for (int i = 0; i < 4; ++i) {
      int lr = wr * 32 + m * 16 + g * 4 + i;
      int t = m0 + lr;
#pragma unroll
      for (int n = 0; n < 4; ++n) {
        int d = n * 16 + lq;
        float val = acc[m][n][i];
        if (part < 2) {
          float cv = cosT[t * DHn + d], sv = sinT[t * DHn + d];
          float partner = acc[m][n ^ 2][i];
          val = (n < 2) ? fmaf(-partner, sv, val * cv) : fmaf(partner, sv, val * cv);
        }
        Lo[lr * 128 + wc * 64 + d] = f2b(val);
      }
    }
  __syncthreads();
#pragma unroll
  for (int it = 0; it < 4; ++it) {
    int c = it * 256 + tid;
    int tr = c >> 4, cc = c & 15;
    int cola = n0 + (cc << 3);
    int pp = cola / Cn;
    int h = (cola % Cn) / DHn;
    int d0 = cola % DHn;
    unsigned short* dst = pp == 0 ? qout : (pp == 1 ? kout : vout);
    *(short8*)(dst + ((size_t)h * Tn + (m0 + tr)) * DHn + d0) = *(const short8*)(Lo + tr * 128 + (cc << 3));
  }
}

// -------- proj GEMM: 64x64 tile, 4 waves (2x2: 32x32), 768 blocks, 2-deep (r13-verified) --------
__global__ __launch_bounds__(256, 4) void k_gproj(const unsigned short* __restrict__ A,
                                                  const unsigned short* __restrict__ BT,
                                                  float* __restrict__ Cout) {
  __shared__ __align__(16) unsigned short Ls[2][8192];
  int tid = threadIdx.x, lane = tid & 63, wave = tid >> 6;
  int lq = lane & 15, g = (lane >> 4) & 3;
  int wr = wave >> 1, wc = wave & 1;
  int nx = gridDim.x;
  int nwg = nx * gridDim.y;
  int lid = blockIdx.y * nx + blockIdx.x;
  int swz = (lid & 7) * (nwg >> 3) + (lid >> 3);
  int bx = swz % nx, by = swz / nx;
  int m0 = by * 64, n0 = bx * 64;
  const unsigned short* Ab = A + (size_t)m0 * Cn;
  const unsigned short* Bb = BT + (size_t)n0 * Cn;
  f32x4 acc[2][2] = {};
  const int NK = Cn >> 6;
  stage_mat<64, 256>(Ab, Cn, Ls[0], 0, tid);
  stage_mat<64, 256>(Bb, Cn, Ls[0] + 4096, 0, tid);
  stage_mat<64, 256>(Ab, Cn, Ls[1], 64, tid);
  stage_mat<64, 256>(Bb, Cn, Ls[1] + 4096, 64, tid);
  for (int kt = 0; kt < NK; ++kt) {
    if (kt + 1 < NK) asm volatile("s_waitcnt vmcnt(4)" ::: "memory");
    else             asm volatile("s_waitcnt vmcnt(0)" ::: "memory");
    __builtin_amdgcn_s_barrier();
    __builtin_amdgcn_sched_barrier(0);
    const unsigned short* Ac = Ls[kt & 1];
    const unsigned short* Bc = Ls[kt & 1] + 4096;
#pragma unroll
    for (int kk = 0; kk < 2; ++kk) {
      short8 a[2], b[2];
#pragma unroll
      for (int m = 0; m < 2; ++m) a[m] = frag_read64(Ac, wr * 32 + m * 16 + lq, kk * 4 + g);
#pragma unroll
      for (int n = 0; n < 2; ++n) b[n] = frag_read64(Bc, wc * 32 + n * 16 + lq, kk * 4 + g);
#pragma unroll
      for (int m = 0; m < 2; ++m)
#pragma unroll
        for (int n = 0; n < 2; ++n)
          acc[m][n] = __builtin_amdgcn_mfma_f32_16x16x32_bf16(a[m], b[n], acc[m][n], 0, 0, 0);
    }
    __builtin_amdgcn_sched_barrier(0);
    __builtin_amdgcn_s_barrier();
    if (kt + 2 < NK) {
      stage_mat<64, 256>(Ab, Cn, Ls[kt & 1], (kt + 2) << 6, tid);
      stage_mat<64, 256>(Bb, Cn, Ls[kt & 1] + 4096, (kt + 2) << 6, tid);
    }
  }
  int r0 = m0 + wr * 32 + g * 4;
  int c0 = n0 + wc * 32 + lq;
#pragma unroll
  for (int m = 0; m < 2; ++m)
#pragma unroll
    for (int n = 0; n < 2; ++n)
#pragma unroll
      for (int i = 0; i < 2 * 2; ++i)
        Cout[(size_t)(r0 + m * 16 + i) * Cn + c0 + n * 16] = acc[m][n][i];
}

// ---- stage NROWS rows (4x16-subtiled layout) via global_load_lds ----
// addr(j,d) = (j>>2)*512 + (d>>4)*128 + (j&3)*32 + (d&15)*2  (bytes)
template<int NROWS>
__device__ __forceinline__ void stage_sub(const unsigned short* __restrict__ srcHead,
                                          int jbase, unsigned short* buf, int tid) {
#pragma unroll
  for (int it = 0; it < NROWS * 8 / 256; ++it) {
    int cc = it * 256 + tid;
    int j = jbase + ((cc >> 5) << 2) + ((cc & 7) >> 1);
    j = j < 0 ? 0 : j;
    int d0 = (((cc >> 3) & 3) << 4) + ((cc & 1) << 3);
    const unsigned short* ga = srcHead + (size_t)j * DHn + d0;
    __builtin_amdgcn_global_load_lds((const __attribute__((address_space(1))) void*)ga,
                                     (__attribute__((address_space(3))) void*)(buf + cc * 8),
                                     16, 0, 0);
  }
}

// ---- PV: NE A-frags x subtiled-V single 192-row buffer (attn_b) ----
__device__ __forceinline__ void pv_tr(const unsigned short* Vt, const short8* af,
                                      int wave, int lane, f32x4* oacc) {
  int lq = lane & 15, g = lane >> 4;
  unsigned base = (unsigned)(size_t)(const __attribute__((address_space(3))) unsigned short*)Vt;
  unsigned pl = base + lq * 8;
#pragma unroll
  for (int e = 0; e < NE; ++e) {
    int kl = 16 * wave + 32 * e + 8 * g;
    if (kl > TJ - 8) kl = TJ - 8;
    unsigned pe = pl + kl * 128;
    unsigned long long rr[8];
#pragma unroll
    for (int dt = 0; dt < 4; ++dt) {
      asm volatile("ds_read_b64_tr_b16 %0, %1" : "=v"(rr[2 * dt]) : "v"(pe + dt * 128));
      asm volatile("ds_read_b64_tr_b16 %0, %1" : "=v"(rr[2 * dt + 1]) : "v"(pe + dt * 128 + 512));
    }
    asm volatile("s_waitcnt lgkmcnt(0)");
    __builtin_amdgcn_sched_barrier(0);
#pragma unroll
    for (int dt = 0; dt < 4; ++dt) {
      union { unsigned long long u[2]; short8 s; } vb;
      vb.u[0] = rr[2 * dt]; vb.u[1] = rr[2 * dt + 1];
      oacc[dt] = __builtin_amdgcn_mfma_f32_16x16x32_bf16(af[e], vb.s, oacc[dt], 0, 0, 0);
    }
  }
}

// ---- PV: NE A-frags x subtiled-V in 128-row B0 + 64-row B1 (attn_a) ----
__device__ __forceinline__ void pv_tr2(const unsigned short* V0h, const unsigned short* V1h,
                                       const short8* af, int wave, int lane, f32x4* oacc) {
  int lq = lane & 15, g = lane >> 4;
  unsigned b0 = (unsigned)(size_t)(const __attribute__((address_space(3))) unsigned short*)V0h;
  unsigned b1 = (unsigned)(size_t)(const __attribute__((address_space(3))) unsigned short*)V1h;
#pragma unroll
  for (int e = 0; e < NE; ++e) {
    int kl = 16 * wave + 32 * e + 8 * g;
    if (kl > TJ - 8) kl = TJ - 8;
    unsigned base = (kl < 128) ? b0 : b1;
    int klo = (kl < 128) ? kl : (kl - 128);
    unsigned pe = base + lq * 8 + klo * 128;
    unsigned long long rr[8];
#pragma unroll
    for (int dt = 0; dt < 4; ++dt) {
      asm volatile("ds_read_b64_tr_b16 %0, %1" : "=v"(rr[2 * dt]) : "v"(pe + dt * 128));
      asm volatile("ds_read_b64_tr_b16 %0, %1" : "=v"(rr[2 * dt + 1]) : "v"(pe + dt * 128 + 512));
    }
    asm volatile("s_waitcnt lgkmcnt(0)");
    __builtin_amdgcn_sched_barrier(0);
#pragma unroll
    for (int dt = 0; dt < 4; ++dt) {
      union { unsigned long long u[2]; short8 s; } vb;
      vb.u[0] = rr[2 * dt]; vb.u[1] = rr[2 * dt + 1];
      oacc[dt] = __builtin_amdgcn_mfma_f32_16x16x32_bf16(af[e], vb.s, oacc[dt], 0, 0, 0);
    }
  }
}

// ---------------- pass A: QK^T + softmax; write pv1 and normalized P fragments ----------------
// B0 (128 rows) + B1 (64 rows) time-shared K -> V (24KB LDS); V staging overlapped with softmax.
__global__ __launch_bounds__(256) void k_attn_a(const unsigned short* __restrict__ qr,
                                                const unsigned short* __restrict__ kr,
                                                const unsigned short* __restrict__ vin,
                                                unsigned short* __restrict__ pv1out,
                                                unsigned short* __restrict__ pfrag,
                                                const float* __restrict__ kap_p,
                                                const float* __restrict__ xi_p) {
  __shared__ __align__(16) unsigned short B0[128 * DHn];
  __shared__ __align__(16) unsigned short B1[64 * DHn];
  int tid = threadIdx.x, lane = tid & 63, wave = tid >> 6;
  int lq = lane & 15, g = lane >> 4;
  int i0 = blockIdx.x * QBLK, h = blockIdx.y;
  int jt0 = i0 - BAND;
  const size_t headoff = (size_t)h * Tn * DHn;

  // ---- stage K band (192 rows: B0 first 128, B1 last 64; swizzled row layout)
  const unsigned short* krh = kr + headoff;
#pragma unroll
  for (int it = 0; it < 6; ++it) {
    int c = it * 256 + tid;                // 0..1535
    int row = c >> 3, c8 = c & 7;
    int j = jt0 + row; j = j < 0 ? 0 : j;
    const unsigned short* ga = krh + (size_t)j * DHn + ((c8 ^ (row & 7)) << 3);
    unsigned short* dstb = (row < 128) ? (B0 + c * 8) : (B1 + (c - 1024) * 8);
    __builtin_amdgcn_global_load_lds((const __attribute__((address_space(1))) void*)ga,
                                     (__attribute__((address_space(3))) void*)dstb,
                                     16, 0, 0);
  }

  // Q fragments from global
  const unsigned short* qrh = qr + headoff;
  int q0 = i0 + wave * 16;
  short8 qf0 = *(const short8*)(qrh + (size_t)(q0 + lq) * DHn + g * 8);
  short8 qf1 = *(const short8*)(qrh + (size_t)(q0 + lq) * DHn + 32 + g * 8);
  asm volatile("s_waitcnt vmcnt(0)" ::: "memory");
  __builtin_amdgcn_s_barrier();

  // ---- S^T = K . Q^T over NTW key tiles (half select; rows 0..191)
  f32x4 st[NTW];
#pragma unroll
  for (int t = 0; t < NTW; ++t) st[t] = (f32x4){0.f, 0.f, 0.f, 0.f};
#pragma unroll
  for (int t = 0; t < NTW; ++t) {
    int row = (wave + t) * 16 + lq;
    const char* kb = (row < 128) ? ((const char*)B0 + row * 128)
                                 : ((const char*)B1 + (row - 128) * 128);
    int sw = row & 7;
    short8 ka0 = *(const short8*)(kb + ((g ^ sw) << 4));
    short8 ka1 = *(const short8*)(kb + (((4 + g) ^ sw) << 4));
    st[t] = __builtin_amdgcn_mfma_f32_16x16x32_bf16(ka0, qf0, st[t], 0, 0, 0);
    st[t] = __builtin_amdgcn_mfma_f32_16x16x32_bf16(ka1, qf1, st[t], 0, 0, 0);
  }
  __syncthreads();   // K buffers dead; safe to overwrite with V

  // ---- issue V staging now; latency hides under softmax (T14)
  const unsigned short* vrh = vin + headoff;
  stage_sub<128>(vrh, jt0, B0, tid);
  stage_sub<64>(vrh, jt0 + 128, B1, tid);

  // ---- softmax (log2 domain), lane-local + 2 shfl_xor
  float kap = log1pf(__expf(*kap_p));
  float xi  = log1pf(__expf(*xi_p));
  const float LOG2E = 1.4426950408889634f;
  float sc = 0.125f * LOG2E;
  float c2 = kap / (xi * xi) * LOG2E;
  float db0 = (float)(lq + BAND - 4 * g);
  float jb0 = (float)(jt0 + 16 * wave + 4 * g);
  float m = -3.0e38f;
#pragma unroll
  for (int t = 0; t < NTW; ++t) {
#pragma unroll
    for (int r = 0; r < 4; ++r) {
      float off = (float)(16 * t + r);
      float dist = db0 - off;
      float jv = jb0 + off;
      float l2 = fmaf(dist * dist, -c2, st[t][r] * sc);
      bool bad = (dist < 0.f) || (jv < 0.f);
      l2 = bad ? -3.0e38f : l2;
      st[t][r] = l2;
      m = fmaxf(m, l2);
    }
  }
  m = fmaxf(m, __shfl_xor(m, 16));
  m = fmaxf(m, __shfl_xor(m, 32));
  float sum = 0.f;
#pragma unroll
  for (int t = 0; t < NTW; ++t) {
#pragma unroll
    for (int r = 0; r < 4; ++r) {
      float p = exp2f(st[t][r] - m);
      st[t][r] = p;
      sum += p;
    }
  }
  sum += __shfl_xor(sum, 16);
  sum += __shfl_xor(sum, 32);
  float inv_s = 1.f / sum;

  // pack NORMALIZED P to bf16 pairs
  unsigned int pk0[NTW], pk1[NTW];
#pragma unroll
  for (int t = 0; t < NTW; ++t) {
    pk0[t] = (unsigned int)f2b(st[t][0] * inv_s) | ((unsigned int)f2b(st[t][1] * inv_s) << 16);
    pk1[t] = (unsigned int)f2b(st[t][2] * inv_s) | ((unsigned int)f2b(st[t][3] * inv_s) << 16);
  }

  // redistribute into A-fragments via shfl
  short8 af[NE];
  int srcA = lq + (g & 1) * 32;
  int srcB = srcA + 16;
  bool hiT = (g >= 2);
#pragma unroll
  for (int e = 0; e < NE; ++e) {
    unsigned int aA0 = __shfl(pk0[2 * e], srcA);
    unsigned int aA1 = __shfl(pk1[2 * e], srcA);
    unsigned int aB0 = __shfl(pk0[2 * e], srcB);
    unsigned int aB1 = __shfl(pk1[2 * e], srcB);
    unsigned int dw0, dw1, dw2, dw3;
    if (e < NE - 1) {
      unsigned int bA0 = __shfl(pk0[2 * e + 1], srcA);
      unsigned int bA1 = __shfl(pk1[2 * e + 1], srcA);
      unsigned int bB0 = __shfl(pk0[2 * e + 1], srcB);
      unsigned int bB1 = __shfl(pk1[2 * e + 1], srcB);
      dw0 = hiT ? bA0 : aA0; dw1 = hiT ? bA1 : aA1;
      dw2 = hiT ? bB0 : aB0; dw3 = hiT ? bB1 : aB1;
    } else {
      dw0 = hiT ? 0u : aA0; dw1 = hiT ? 0u : aA1;
      dw2 = hiT ? 0u : aB0; dw3 = hiT ? 0u : aB1;
    }
    union { unsigned int u[4]; short8 s; } t2;
    t2.u[0] = dw0; t2.u[1] = dw1; t2.u[2] = dw2; t2.u[3] = dw3;
    af[e] = t2.s;
  }

  // store P fragments (coalesced 16B/lane)
  size_t pfb = ((((size_t)h * (Tn / QBLK) + blockIdx.x) * 4 + wave) * NE) * 512 + (size_t)lane * 8;
#pragma unroll
  for (int e = 0; e < NE; ++e)
    *(short8*)(pfrag + pfb + (size_t)e * 512) = af[e];

  // ---- V ready -> PV
  asm volatile("s_waitcnt vmcnt(0)" ::: "memory");
  __builtin_amdgcn_s_barrier();
  f32x4 oacc[4];
#pragma unroll
  for (int dt = 0; dt < 4; ++dt) oacc[dt] = (f32x4){0.f, 0.f, 0.f, 0.f};
  pv_tr2(B0, B1, af, wave, lane, oacc);

  // epilogue
#pragma unroll
  for (int dt = 0; dt < 4; ++dt)
#pragma unroll
    for (int r = 0; r < 4; ++r) {
      int i = i0 + 16 * wave + 4 * g + r;
      pv1out[headoff + (size_t)i * DHn + dt * 16 + lq] = f2b(oacc[dt][r]);
    }
}

// ---------------- pass B: pv2 = P @ pv1 (P from stored frags); combine -> y[T][C] ----------------
__global__ __launch_bounds__(256) void k_attn_b(const unsigned short* __restrict__ pv1,
                                                const unsigned short* __restrict__ v0,
                                                const unsigned short* __restrict__ pfrag,
                                                unsigned short* __restrict__ yout,
                                                const float* __restrict__ dt_logit_p) {
  __shared__ __align__(16) unsigned short Vt[TJ * DHn];   // 24KB subtiled pv1 tile
  int tid = threadIdx.x, lane = tid & 63, wave = tid >> 6;
  int lq = lane & 15, g = lane >> 4;
  int i0 = blockIdx.x * QBLK, h = blockIdx.y;
  int jt0 = i0 - BAND;
  const size_t headoff = (size_t)h * Tn * DHn;

  stage_sub<TJ>(pv1 + headoff, jt0, Vt, tid);

  // load P fragments
  short8 af[NE];
  size_t pfb = ((((size_t)h * (Tn / QBLK) + blockIdx.x) * 4 + wave) * NE) * 512 + (size_t)lane * 8;
#pragma unroll
  for (int e = 0; e < NE; ++e)
    af[e] = *(const short8*)(pfrag + pfb + (size_t)e * 512);
  asm volatile("s_waitcnt vmcnt(0)" ::: "memory");
  __builtin_amdgcn_s_barrier();

  f32x4 oacc[4];
#pragma unroll
  for (int dt = 0; dt < 4; ++dt) oacc[dt] = (f32x4){0.f, 0.f, 0.f, 0.f};
  pv_tr(Vt, af, wave, lane, oacc);

  float dtv = 1.f / (1.f + __expf(-*dt_logit_p));
  float a1 = dtv, a2 = 0.5f * dtv * dtv;
  float inv3 = 1.f / (1.f + a1 + a2);
  float w0 = inv3, w1 = a1 * inv3, w2 = a2 * inv3;

#pragma unroll
  for (int dt = 0; dt < 4; ++dt)
#pragma unroll
    for (int r = 0; r < 4; ++r) {
      int i = i0 + 16 * wave + 4 * g + r;
      // pv1[i][d] from the staged subtiled tile (row BAND + i-i0)
      int j = BAND + 16 * wave + 4 * g + r;
      unsigned boff = (unsigned)((j >> 2) * 512 + dt * 128 + (j & 3) * 32 + lq * 2);
      float p1 = b2f(*(const unsigned short*)((const char*)Vt + boff));
      float vv = b2f(v0[headoff + (size_t)i * DHn + dt * 16 + lq]);
      float yv = w0 * vv + w1 * p1 + w2 * oacc[dt][r];
      yout[(size_t)i * Cn + h * DHn + dt * 16 + lq] = f2b(yv);
    }
}

extern "C" void kernel_launch(void* const* d_in, const int* in_sizes, int n_in,
                              void* d_out, int out_size, void* d_ws, size_t ws_size,
                              hipStream_t stream) {
  (void)in_sizes; (void)n_in; (void)out_size; (void)ws_size;
  const float* x     = (const float*)d_in[0];
  const float* cosT  = (const float*)d_in[1];
  const float* sinT  = (const float*)d_in[2];
  const float* Wqkv  = (const float*)d_in[3];
  const float* Wproj = (const float*)d_in[4];
  const float* dtl   = (const float*)d_in[5];
  const float* kap   = (const float*)d_in[6];
  const float* xiu   = (const float*)d_in[7];
  float* out = (float*)d_out;
  char* ws = (char*)d_ws;
  size_t off = 0;
  auto alloc = [&](size_t bytes) { char* p = ws + off; off += (bytes + 255) & ~(size_t)255; return p; };
  unsigned short* x_bf   = (unsigned short*)alloc((size_t)Tn * Cn * 2);
  unsigned short* WqkvT  = (unsigned short*)alloc((size_t)3 * Cn * Cn * 2);
  unsigned short* WprojT = (unsigned short*)alloc((size_t)Cn * Cn * 2);
  unsigned short* q_r    = (unsigned short*)alloc((size_t)Hn * Tn * DHn * 2);
  unsigned short* k_r    = (unsigned short*)alloc((size_t)Hn * Tn * DHn * 2);
  unsigned short* v_s    = (unsigned short*)alloc((size_t)Hn * Tn * DHn * 2);
  unsigned short* pv1    = (unsigned short*)alloc((size_t)Hn * Tn * DHn * 2);
  unsigned short* y_bf   = (unsigned short*)alloc((size_t)Tn * Cn * 2);
  unsigned short* pfrag  = (unsigned short*)alloc((size_t)Hn * (Tn / QBLK) * 4 * NE * 512 * 2);

  k_prep<<<2816, 256, 0, stream>>>(x, x_bf, Wqkv, WqkvT, Wproj, WprojT);
  k_gqkv<<<dim3(3 * Cn / 128, Tn / 64), 256, 0, stream>>>(
      x_bf, WqkvT, cosT, sinT, q_r, k_r, v_s);
  k_attn_a<<<dim3(Tn / QBLK, Hn), 256, 0, stream>>>(q_r, k_r, v_s, pv1, pfrag, kap, xiu);
  k_attn_b<<<dim3(Tn / QBLK, Hn), 256, 0, stream>>>(pv1, v_s, pfrag, y_bf, dtl);
  k_gproj<<<dim3(Cn / 64, Tn / 64), 256, 0, stream>>>(y_bf, WprojT, out);
}

// Round 19
// 76.342 us; speedup vs baseline: 1.0302x; 1.0302x over previous
//
#include <hip/hip_runtime.h>
#include <hip/hip_bf16.h>

#define Tn 4096
#define Cn 768
#define Hn 12
#define DHn 64
#define BAND 128
#define QBLK 64
#define TJ 192        // BAND + QBLK staged keys per block
#define NTW 9         // 16-key tiles per wave (band window)
#define NE 5          // PV e-steps (32 keys each)

typedef __attribute__((ext_vector_type(8))) short short8;
typedef __attribute__((ext_vector_type(4))) short short4v;
typedef __attribute__((ext_vector_type(4))) float f32x4;

__device__ __forceinline__ float b2f(unsigned short u) {
  union { unsigned int i; float f; } z; z.i = ((unsigned int)u) << 16; return z.f;
}
__device__ __forceinline__ unsigned short f2b(float f) {
  union { float f; unsigned int i; } z; z.f = f;
  unsigned int r = z.i + 0x7FFFu + ((z.i >> 16) & 1u);
  return (unsigned short)(r >> 16);
}

// ---------------- prep: f32->bf16 convert + both weight transposes ----------------
__global__ __launch_bounds__(256) void k_prep(const float* __restrict__ x,
                                              unsigned short* __restrict__ x_bf,
                                              const float* __restrict__ Wqkv,
                                              unsigned short* __restrict__ WqkvT,
                                              const float* __restrict__ Wproj,
                                              unsigned short* __restrict__ WprojT) {
  __shared__ float tile[32][33];
  int b = blockIdx.x, tid = threadIdx.x;
  if (b < 512) {
    int n4 = Tn * Cn / 4;
    for (int i = b * 256 + tid; i < n4; i += 512 * 256) {
      float4 v = ((const float4*)x)[i];
      short4v o;
      o.x = (short)f2b(v.x); o.y = (short)f2b(v.y);
      o.z = (short)f2b(v.z); o.w = (short)f2b(v.w);
      ((short4v*)x_bf)[i] = o;
    }
    return;
  }
  const float* W; unsigned short* WT; int N, r;
  if (b < 2240) { r = b - 512; W = Wqkv; WT = WqkvT; N = 3 * Cn; }
  else          { r = b - 2240; W = Wproj; WT = WprojT; N = Cn; }
  int nb = N / 32;
  int n0 = (r % nb) * 32, k0 = (r / nb) * 32;
  int tx = tid & 31, ty = tid >> 5;   // 32 x 8
  for (int rr = ty; rr < 32; rr += 8) tile[rr][tx] = W[(size_t)(k0 + rr) * N + n0 + tx];
  __syncthreads();
  for (int rr = ty; rr < 32; rr += 8) WT[(size_t)(n0 + rr) * Cn + k0 + tx] = f2b(tile[tx][rr]);
}

// ======== GEMM building blocks: BK=64, swizzled LDS rows (8 slots of 16B, involution) ========
template<int ROWS, int NTHR>
__device__ __forceinline__ void stage_mat(const unsigned short* __restrict__ Gb,
                                          int K, unsigned short* buf, int k0, int tid) {
  constexpr int CHUNKS = ROWS * 8;
#pragma unroll
  for (int it = 0; it < CHUNKS / NTHR; ++it) {
    int c = it * NTHR + tid;
    int row = c >> 3;
    int kc = (c & 7) ^ (row & 7);
    const unsigned short* ga = Gb + (size_t)row * K + k0 + kc * 8;
    __builtin_amdgcn_global_load_lds((const __attribute__((address_space(1))) void*)ga,
                                     (__attribute__((address_space(3))) void*)(buf + c * 8),
                                     16, 0, 0);
  }
}

__device__ __forceinline__ short8 frag_read64(const unsigned short* buf, int row, int q) {
  int s = q ^ (row & 7);
  return *(const short8*)(buf + row * 64 + s * 8);
}

// -------- QKV GEMM: 64x128 tile, single-buffered simple loop, 24KB LDS, 4 blocks/CU --------
__global__ __launch_bounds__(256, 4) void k_gqkv(const unsigned short* __restrict__ A,
                                                 const unsigned short* __restrict__ BT,
                                                 const float* __restrict__ cosT,
                                                 const float* __restrict__ sinT,
                                                 unsigned short* __restrict__ qout,
                                                 unsigned short* __restrict__ kout,
                                                 unsigned short* __restrict__ vout) {
  __shared__ __align__(16) unsigned short Ls[12288];   // A 64x64 | B 128x64
  int tid = threadIdx.x, lane = tid & 63, wave = tid >> 6;
  int lq = lane & 15, g = (lane >> 4) & 3;
  int wr = wave >> 1, wc = wave & 1;
  int nx = gridDim.x;
  int nwg = nx * gridDim.y;
  int lid = blockIdx.y * nx + blockIdx.x;
  int swz = (lid & 7) * (nwg >> 3) + (lid >> 3);
  int bx = swz % nx, by = swz / nx;
  int m0 = by * 64, n0 = bx * 128;
  const unsigned short* Ab = A + (size_t)m0 * Cn;
  const unsigned short* Bb = BT + (size_t)n0 * Cn;
  f32x4 acc[2][4] = {};
  const int NK = Cn >> 6;                     // 12
  for (int kt = 0; kt < NK; ++kt) {
    stage_mat<64, 256>(Ab, Cn, Ls, kt << 6, tid);
    stage_mat<128, 256>(Bb, Cn, Ls + 4096, kt << 6, tid);
    __syncthreads();
    const unsigned short* Ac = Ls;
    const unsigned short* Bc = Ls + 4096;
#pragma unroll
    for (int kk = 0; kk < 2; ++kk) {
      short8 a[2], b[4];
#pragma unroll
      for (int m = 0; m < 2; ++m) a[m] = frag_read64(Ac, wr * 32 + m * 16 + lq, kk * 4 + g);
#pragma unroll
      for (int n = 0; n < 4; ++n) b[n] = frag_read64(Bc, wc * 64 + n * 16 + lq, kk * 4 + g);
#pragma unroll
      for (int m = 0; m < 2; ++m)
#pragma unroll
        for (int n = 0; n < 4; ++n)
          acc[m][n] = __builtin_amdgcn_mfma_f32_16x16x32_bf16(a[m], b[n], acc[m][n], 0, 0, 0);
    }
    __syncthreads();
  }
  // epilogue: RoPE in-register, scatter to LDS, coalesced stores
  int col0 = n0 + wc * 64;
  int part = col0 / Cn;
  unsigned short* Lo = (unsigned short*)Ls;
#pragma unroll
  for (int m = 0; m < 2; ++m)
#pragma unroll
    for (int i = 0; i < 4; ++i) {
      int lr = wr * 32 + m * 16 + g * 4 + i;
      int t = m0 + lr;
#pragma unroll
      for (int n = 0; n < 4; ++n) {
        int d = n * 16 + lq;
        float val = acc[m][n][i];
        if (part < 2) {
          float cv = cosT[t * DHn + d], sv = sinT[t * DHn + d];
          float partner = acc[m][n ^ 2][i];
          val = (n < 2) ? fmaf(-partner, sv, val * cv) : fmaf(partner, sv, val * cv);
        }
        Lo[lr * 128 + wc * 64 + d] = f2b(val);
      }
    }
  __syncthreads();
#pragma unroll
  for (int it = 0; it < 4; ++it) {
    int c = it * 256 + tid;
    int tr = c >> 4, cc = c & 15;
    int cola = n0 + (cc << 3);
    int pp = cola / Cn;
    int h = (cola % Cn) / DHn;
    int d0 = cola % DHn;
    unsigned short* dst = pp == 0 ? qout : (pp == 1 ? kout : vout);
    *(short8*)(dst + ((size_t)h * Tn + (m0 + tr)) * DHn + d0) = *(const short8*)(Lo + tr * 128 + (cc << 3));
  }
}

// -------- proj GEMM: 64x64 tile, 4 waves (2x2: 32x32), 768 blocks, 2-deep (r13-verified) --------
__global__ __launch_bounds__(256, 4) void k_gproj(const unsigned short* __restrict__ A,
                                                  const unsigned short* __restrict__ BT,
                                                  float* __restrict__ Cout) {
  __shared__ __align__(16) unsigned short Ls[2][8192];
  int tid = threadIdx.x, lane = tid & 63, wave = tid >> 6;
  int lq = lane & 15, g = (lane >> 4) & 3;
  int wr = wave >> 1, wc = wave & 1;
  int nx = gridDim.x;
  int nwg = nx * gridDim.y;
  int lid = blockIdx.y * nx + blockIdx.x;
  int swz = (lid & 7) * (nwg >> 3) + (lid >> 3);
  int bx = swz % nx, by = swz / nx;
  int m0 = by * 64, n0 = bx * 64;
  const unsigned short* Ab = A + (size_t)m0 * Cn;
  const unsigned short* Bb = BT + (size_t)n0 * Cn;
  f32x4 acc[2][2] = {};
  const int NK = Cn >> 6;
  stage_mat<64, 256>(Ab, Cn, Ls[0], 0, tid);
  stage_mat<64, 256>(Bb, Cn, Ls[0] + 4096, 0, tid);
  stage_mat<64, 256>(Ab, Cn, Ls[1], 64, tid);
  stage_mat<64, 256>(Bb, Cn, Ls[1] + 4096, 64, tid);
  for (int kt = 0; kt < NK; ++kt) {
    if (kt + 1 < NK) asm volatile("s_waitcnt vmcnt(4)" ::: "memory");
    else             asm volatile("s_waitcnt vmcnt(0)" ::: "memory");
    __builtin_amdgcn_s_barrier();
    __builtin_amdgcn_sched_barrier(0);
    const unsigned short* Ac = Ls[kt & 1];
    const unsigned short* Bc = Ls[kt & 1] + 4096;
#pragma unroll
    for (int kk = 0; kk < 2; ++kk) {
      short8 a[2], b[2];
#pragma unroll
      for (int m = 0; m < 2; ++m) a[m] = frag_read64(Ac, wr * 32 + m * 16 + lq, kk * 4 + g);
#pragma unroll
      for (int n = 0; n < 2; ++n) b[n] = frag_read64(Bc, wc * 32 + n * 16 + lq, kk * 4 + g);
#pragma unroll
      for (int m = 0; m < 2; ++m)
#pragma unroll
        for (int n = 0; n < 2; ++n)
          acc[m][n] = __builtin_amdgcn_mfma_f32_16x16x32_bf16(a[m], b[n], acc[m][n], 0, 0, 0);
    }
    __builtin_amdgcn_sched_barrier(0);
    __builtin_amdgcn_s_barrier();
    if (kt + 2 < NK) {
      stage_mat<64, 256>(Ab, Cn, Ls[kt & 1], (kt + 2) << 6, tid);
      stage_mat<64, 256>(Bb, Cn, Ls[kt & 1] + 4096, (kt + 2) << 6, tid);
    }
  }
  int r0 = m0 + wr * 32 + g * 4;
  int c0 = n0 + wc * 32 + lq;
#pragma unroll
  for (int m = 0; m < 2; ++m)
#pragma unroll
    for (int n = 0; n < 2; ++n)
#pragma unroll
      for (int i = 0; i < 2 * 2; ++i)
        Cout[(size_t)(r0 + m * 16 + i) * Cn + c0 + n * 16] = acc[m][n][i];
}

// ---- stage NROWS rows (4x16-subtiled layout) via global_load_lds ----
// addr(j,d) = (j>>2)*512 + (d>>4)*128 + (j&3)*32 + (d&15)*2  (bytes)
template<int NROWS>
__device__ __forceinline__ void stage_sub(const unsigned short* __restrict__ srcHead,
                                          int jbase, unsigned short* buf, int tid) {
#pragma unroll
  for (int it = 0; it < NROWS * 8 / 256; ++it) {
    int cc = it * 256 + tid;
    int j = jbase + ((cc >> 5) << 2) + ((cc & 7) >> 1);
    j = j < 0 ? 0 : j;
    int d0 = (((cc >> 3) & 3) << 4) + ((cc & 1) << 3);
    const unsigned short* ga = srcHead + (size_t)j * DHn + d0;
    __builtin_amdgcn_global_load_lds((const __attribute__((address_space(1))) void*)ga,
                                     (__attribute__((address_space(3))) void*)(buf + cc * 8),
                                     16, 0, 0);
  }
}

// ---- PV: NE A-frags x subtiled-V single 192-row buffer (attn_b) ----
__device__ __forceinline__ void pv_tr(const unsigned short* Vt, const short8* af,
                                      int wave, int lane, f32x4* oacc) {
  int lq = lane & 15, g = lane >> 4;
  unsigned base = (unsigned)(size_t)(const __attribute__((address_space(3))) unsigned short*)Vt;
  unsigned pl = base + lq * 8;
#pragma unroll
  for (int e = 0; e < NE; ++e) {
    int kl = 16 * wave + 32 * e + 8 * g;
    if (kl > TJ - 8) kl = TJ - 8;
    unsigned pe = pl + kl * 128;
    unsigned long long rr[8];
#pragma unroll
    for (int dt = 0; dt < 4; ++dt) {
      asm volatile("ds_read_b64_tr_b16 %0, %1" : "=v"(rr[2 * dt]) : "v"(pe + dt * 128));
      asm volatile("ds_read_b64_tr_b16 %0, %1" : "=v"(rr[2 * dt + 1]) : "v"(pe + dt * 128 + 512));
    }
    asm volatile("s_waitcnt lgkmcnt(0)");
    __builtin_amdgcn_sched_barrier(0);
#pragma unroll
    for (int dt = 0; dt < 4; ++dt) {
      union { unsigned long long u[2]; short8 s; } vb;
      vb.u[0] = rr[2 * dt]; vb.u[1] = rr[2 * dt + 1];
      oacc[dt] = __builtin_amdgcn_mfma_f32_16x16x32_bf16(af[e], vb.s, oacc[dt], 0, 0, 0);
    }
  }
}

// ---- PV: NE A-frags x subtiled-V in 128-row B0 + 64-row B1 (attn_a) ----
__device__ __forceinline__ void pv_tr2(const unsigned short* V0h, const unsigned short* V1h,
                                       const short8* af, int wave, int lane, f32x4* oacc) {
  int lq = lane & 15, g = lane >> 4;
  unsigned b0 = (unsigned)(size_t)(const __attribute__((address_space(3))) unsigned short*)V0h;
  unsigned b1 = (unsigned)(size_t)(const __attribute__((address_space(3))) unsigned short*)V1h;
#pragma unroll
  for (int e = 0; e < NE; ++e) {
    int kl = 16 * wave + 32 * e + 8 * g;
    if (kl > TJ - 8) kl = TJ - 8;
    unsigned base = (kl < 128) ? b0 : b1;
    int klo = (kl < 128) ? kl : (kl - 128);
    unsigned pe = base + lq * 8 + klo * 128;
    unsigned long long rr[8];
#pragma unroll
    for (int dt = 0; dt < 4; ++dt) {
      asm volatile("ds_read_b64_tr_b16 %0, %1" : "=v"(rr[2 * dt]) : "v"(pe + dt * 128));
      asm volatile("ds_read_b64_tr_b16 %0, %1" : "=v"(rr[2 * dt + 1]) : "v"(pe + dt * 128 + 512));
    }
    asm volatile("s_waitcnt lgkmcnt(0)");
    __builtin_amdgcn_sched_barrier(0);
#pragma unroll
    for (int dt = 0; dt < 4; ++dt) {
      union { unsigned long long u[2]; short8 s; } vb;
      vb.u[0] = rr[2 * dt]; vb.u[1] = rr[2 * dt + 1];
      oacc[dt] = __builtin_amdgcn_mfma_f32_16x16x32_bf16(af[e], vb.s, oacc[dt], 0, 0, 0);
    }
  }
}

// ---------------- pass A: QK^T + softmax; write pv1 and normalized P fragments ----------------
// B0 (128 rows) + B1 (64 rows) time-shared K -> V (24KB LDS); V staging overlapped with softmax.
__global__ __launch_bounds__(256) void k_attn_a(const unsigned short* __restrict__ qr,
                                                const unsigned short* __restrict__ kr,
                                                const unsigned short* __restrict__ vin,
                                                unsigned short* __restrict__ pv1out,
                                                unsigned short* __restrict__ pfrag,
                                                const float* __restrict__ kap_p,
                                                const float* __restrict__ xi_p) {
  __shared__ __align__(16) unsigned short B0[128 * DHn];
  __shared__ __align__(16) unsigned short B1[64 * DHn];
  int tid = threadIdx.x, lane = tid & 63, wave = tid >> 6;
  int lq = lane & 15, g = lane >> 4;
  int i0 = blockIdx.x * QBLK, h = blockIdx.y;
  int jt0 = i0 - BAND;
  const size_t headoff = (size_t)h * Tn * DHn;

  // ---- stage K band (192 rows: B0 first 128, B1 last 64; swizzled row layout)
  const unsigned short* krh = kr + headoff;
#pragma unroll
  for (int it = 0; it < 6; ++it) {
    int c = it * 256 + tid;                // 0..1535
    int row = c >> 3, c8 = c & 7;
    int j = jt0 + row; j = j < 0 ? 0 : j;
    const unsigned short* ga = krh + (size_t)j * DHn + ((c8 ^ (row & 7)) << 3);
    unsigned short* dstb = (row < 128) ? (B0 + c * 8) : (B1 + (c - 1024) * 8);
    __builtin_amdgcn_global_load_lds((const __attribute__((address_space(1))) void*)ga,
                                     (__attribute__((address_space(3))) void*)dstb,
                                     16, 0, 0);
  }

  // Q fragments from global
  const unsigned short* qrh = qr + headoff;
  int q0 = i0 + wave * 16;
  short8 qf0 = *(const short8*)(qrh + (size_t)(q0 + lq) * DHn + g * 8);
  short8 qf1 = *(const short8*)(qrh + (size_t)(q0 + lq) * DHn + 32 + g * 8);
  asm volatile("s_waitcnt vmcnt(0)" ::: "memory");
  __builtin_amdgcn_s_barrier();

  // ---- S^T = K . Q^T over NTW key tiles (half select; rows 0..191)
  f32x4 st[NTW];
#pragma unroll
  for (int t = 0; t < NTW; ++t) st[t] = (f32x4){0.f, 0.f, 0.f, 0.f};
#pragma unroll
  for (int t = 0; t < NTW; ++t) {
    int row = (wave + t) * 16 + lq;
    const char* kb = (row < 128) ? ((const char*)B0 + row * 128)
                                 : ((const char*)B1 + (row - 128) * 128);
    int sw = row & 7;
    short8 ka0 = *(const short8*)(kb + ((g ^ sw) << 4));
    short8 ka1 = *(const short8*)(kb + (((4 + g) ^ sw) << 4));
    st[t] = __builtin_amdgcn_mfma_f32_16x16x32_bf16(ka0, qf0, st[t], 0, 0, 0);
    st[t] = __builtin_amdgcn_mfma_f32_16x16x32_bf16(ka1, qf1, st[t], 0, 0, 0);
  }
  __syncthreads();   // K buffers dead; safe to overwrite with V

  // ---- issue V staging now; latency hides under softmax (T14)
  const unsigned short* vrh = vin + headoff;
  stage_sub<128>(vrh, jt0, B0, tid);
  stage_sub<64>(vrh, jt0 + 128, B1, tid);

  // ---- softmax (log2 domain), lane-local + 2 shfl_xor
  float kap = log1pf(__expf(*kap_p));
  float xi  = log1pf(__expf(*xi_p));
  const float LOG2E = 1.4426950408889634f;
  float sc = 0.125f * LOG2E;
  float c2 = kap / (xi * xi) * LOG2E;
  float db0 = (float)(lq + BAND - 4 * g);
  float jb0 = (float)(jt0 + 16 * wave + 4 * g);
  float m = -3.0e38f;
#pragma unroll
  for (int t = 0; t < NTW; ++t) {
#pragma unroll
    for (int r = 0; r < 4; ++r) {
      float off = (float)(16 * t + r);
      float dist = db0 - off;
      float jv = jb0 + off;
      float l2 = fmaf(dist * dist, -c2, st[t][r] * sc);
      bool bad = (dist < 0.f) || (jv < 0.f);
      l2 = bad ? -3.0e38f : l2;
      st[t][r] = l2;
      m = fmaxf(m, l2);
    }
  }
  m = fmaxf(m, __shfl_xor(m, 16));
  m = fmaxf(m, __shfl_xor(m, 32));
  float sum = 0.f;
#pragma unroll
  for (int t = 0; t < NTW; ++t) {
#pragma unroll
    for (int r = 0; r < 4; ++r) {
      float p = exp2f(st[t][r] - m);
      st[t][r] = p;
      sum += p;
    }
  }
  sum += __shfl_xor(sum, 16);
  sum += __shfl_xor(sum, 32);
  float inv_s = 1.f / sum;

  // pack NORMALIZED P to bf16 pairs
  unsigned int pk0[NTW], pk1[NTW];
#pragma unroll
  for (int t = 0; t < NTW; ++t) {
    pk0[t] = (unsigned int)f2b(st[t][0] * inv_s) | ((unsigned int)f2b(st[t][1] * inv_s) << 16);
    pk1[t] = (unsigned int)f2b(st[t][2] * inv_s) | ((unsigned int)f2b(st[t][3] * inv_s) << 16);
  }

  // redistribute into A-fragments via shfl
  short8 af[NE];
  int srcA = lq + (g & 1) * 32;
  int srcB = srcA + 16;
  bool hiT = (g >= 2);
#pragma unroll
  for (int e = 0; e < NE; ++e) {
    unsigned int aA0 = __shfl(pk0[2 * e], srcA);
    unsigned int aA1 = __shfl(pk1[2 * e], srcA);
    unsigned int aB0 = __shfl(pk0[2 * e], srcB);
    unsigned int aB1 = __shfl(pk1[2 * e], srcB);
    unsigned int dw0, dw1, dw2, dw3;
    if (e < NE - 1) {
      unsigned int bA0 = __shfl(pk0[2 * e + 1], srcA);
      unsigned int bA1 = __shfl(pk1[2 * e + 1], srcA);
      unsigned int bB0 = __shfl(pk0[2 * e + 1], srcB);
      unsigned int bB1 = __shfl(pk1[2 * e + 1], srcB);
      dw0 = hiT ? bA0 : aA0; dw1 = hiT ? bA1 : aA1;
      dw2 = hiT ? bB0 : aB0; dw3 = hiT ? bB1 : aB1;
    } else {
      dw0 = hiT ? 0u : aA0; dw1 = hiT ? 0u : aA1;
      dw2 = hiT ? 0u : aB0; dw3 = hiT ? 0u : aB1;
    }
    union { unsigned int u[4]; short8 s; } t2;
    t2.u[0] = dw0; t2.u[1] = dw1; t2.u[2] = dw2; t2.u[3] = dw3;
    af[e] = t2.s;
  }

  // store P fragments (coalesced 16B/lane)
  size_t pfb = ((((size_t)h * (Tn / QBLK) + blockIdx.x) * 4 + wave) * NE) * 512 + (size_t)lane * 8;
#pragma unroll
  for (int e = 0; e < NE; ++e)
    *(short8*)(pfrag + pfb + (size_t)e * 512) = af[e];

  // ---- V ready -> PV
  asm volatile("s_waitcnt vmcnt(0)" ::: "memory");
  __builtin_amdgcn_s_barrier();
  f32x4 oacc[4];
#pragma unroll
  for (int dt = 0; dt < 4; ++dt) oacc[dt] = (f32x4){0.f, 0.f, 0.f, 0.f};
  pv_tr2(B0, B1, af, wave, lane, oacc);

  // epilogue
#pragma unroll
  for (int dt = 0; dt < 4; ++dt)
#pragma unroll
    for (int r = 0; r < 4; ++r) {
      int i = i0 + 16 * wave + 4 * g + r;
      pv1out[headoff + (size_t)i * DHn + dt * 16 + lq] = f2b(oacc[dt][r]);
    }
}

// ---------------- pass B: pv2 = P @ pv1 (P from stored frags); combine -> y[T][C] ----------------
__global__ __launch_bounds__(256) void k_attn_b(const unsigned short* __restrict__ pv1,
                                                const unsigned short* __restrict__ v0,
                                                const unsigned short* __restrict__ pfrag,
                                                unsigned short* __restrict__ yout,
                                                const float* __restrict__ dt_logit_p) {
  __shared__ __align__(16) unsigned short Vt[TJ * DHn];   // 24KB subtiled pv1 tile
  int tid = threadIdx.x, lane = tid & 63, wave = tid >> 6;
  int lq = lane & 15, g = lane >> 4;
  int i0 = blockIdx.x * QBLK, h = blockIdx.y;
  int jt0 = i0 - BAND;
  const size_t headoff = (size_t)h * Tn * DHn;

  stage_sub<TJ>(pv1 + headoff, jt0, Vt, tid);

  // load P fragments
  short8 af[NE];
  size_t pfb = ((((size_t)h * (Tn / QBLK) + blockIdx.x) * 4 + wave) * NE) * 512 + (size_t)lane * 8;
#pragma unroll
  for (int e = 0; e < NE; ++e)
    af[e] = *(const short8*)(pfrag + pfb + (size_t)e * 512);
  asm volatile("s_waitcnt vmcnt(0)" ::: "memory");
  __builtin_amdgcn_s_barrier();

  f32x4 oacc[4];
#pragma unroll
  for (int dt = 0; dt < 4; ++dt) oacc[dt] = (f32x4){0.f, 0.f, 0.f, 0.f};
  pv_tr(Vt, af, wave, lane, oacc);

  float dtv = 1.f / (1.f + __expf(-*dt_logit_p));
  float a1 = dtv, a2 = 0.5f * dtv * dtv;
  float inv3 = 1.f / (1.f + a1 + a2);
  float w0 = inv3, w1 = a1 * inv3, w2 = a2 * inv3;

#pragma unroll
  for (int dt = 0; dt < 4; ++dt)
#pragma unroll
    for (int r = 0; r < 4; ++r) {
      int i = i0 + 16 * wave + 4 * g + r;
      // pv1[i][d] from the staged subtiled tile (row BAND + i-i0)
      int j = BAND + 16 * wave + 4 * g + r;
      unsigned boff = (unsigned)((j >> 2) * 512 + dt * 128 + (j & 3) * 32 + lq * 2);
      float p1 = b2f(*(const unsigned short*)((const char*)Vt + boff));
      float vv = b2f(v0[headoff + (size_t)i * DHn + dt * 16 + lq]);
      float yv = w0 * vv + w1 * p1 + w2 * oacc[dt][r];
      yout[(size_t)i * Cn + h * DHn + dt * 16 + lq] = f2b(yv);
    }
}

extern "C" void kernel_launch(void* const* d_in, const int* in_sizes, int n_in,
                              void* d_out, int out_size, void* d_ws, size_t ws_size,
                              hipStream_t stream) {
  (void)in_sizes; (void)n_in; (void)out_size; (void)ws_size;
  const float* x     = (const float*)d_in[0];
  const float* cosT  = (const float*)d_in[1];
  const float* sinT  = (const float*)d_in[2];
  const float* Wqkv  = (const float*)d_in[3];
  const float* Wproj = (const float*)d_in[4];
  const float* dtl   = (const float*)d_in[5];
  const float* kap   = (const float*)d_in[6];
  const float* xiu   = (const float*)d_in[7];
  float* out = (float*)d_out;
  char* ws = (char*)d_ws;
  size_t off = 0;
  auto alloc = [&](size_t bytes) { char* p = ws + off; off += (bytes + 255) & ~(size_t)255; return p; };
  unsigned short* x_bf   = (unsigned short*)alloc((size_t)Tn * Cn * 2);
  unsigned short* WqkvT  = (unsigned short*)alloc((size_t)3 * Cn * Cn * 2);
  unsigned short* WprojT = (unsigned short*)alloc((size_t)Cn * Cn * 2);
  unsigned short* q_r    = (unsigned short*)alloc((size_t)Hn * Tn * DHn * 2);
  unsigned short* k_r    = (unsigned short*)alloc((size_t)Hn * Tn * DHn * 2);
  unsigned short* v_s    = (unsigned short*)alloc((size_t)Hn * Tn * DHn * 2);
  unsigned short* pv1    = (unsigned short*)alloc((size_t)Hn * Tn * DHn * 2);
  unsigned short* y_bf   = (unsigned short*)alloc((size_t)Tn * Cn * 2);
  unsigned short* pfrag  = (unsigned short*)alloc((size_t)Hn * (Tn / QBLK) * 4 * NE * 512 * 2);

  k_prep<<<2816, 256, 0, stream>>>(x, x_bf, Wqkv, WqkvT, Wproj, WprojT);
  k_gqkv<<<dim3(3 * Cn / 128, Tn / 64), 256, 0, stream>>>(
      x_bf, WqkvT, cosT, sinT, q_r, k_r, v_s);
  k_attn_a<<<dim3(Tn / QBLK, Hn), 256, 0, stream>>>(q_r, k_r, v_s, pv1, pfrag, kap, xiu);
  k_attn_b<<<dim3(Tn / QBLK, Hn), 256, 0, stream>>>(pv1, v_s, pfrag, y_bf, dtl);
  k_gproj<<<dim3(Cn / 64, Tn / 64), 256, 0, stream>>>(y_bf, WprojT, out);
}